// Round 10
// baseline (172.667 us; speedup 1.0000x reference)
//
#include <hip/hip_runtime.h>
#include <hip/hip_fp16.h>

// dot_attention: out[b,n] = exp(diag*s - lse_n), s = (D/2)^-0.5 = 1/16.
// B=4, N=4096, D=512. Inputs fp32, output fp32.
// No fp32 MFMA on CDNA4 -> fp16 convert + MFMA.
//
// R17: switch 16x16x32 -> 32x32x16 MFMA (mix change, not schedule change).
//  - R8/R10/R15 (schedules), R9/R11 (occupancy/M), R13 (fusion), R16
//    (anti-phase): all neutral/worse -> iter time not schedule-addressable.
//  - 32x32x16 does the same FLOPs in 17% fewer matrix cycles (m119:
//    2495 vs 2075 TF) and halves MFMA+wait instruction count; LDS bytes
//    and register budget unchanged (Af 128 VGPR, acc 16, 32KB tile/wave).
//  - Layouts: B-frag col=lane&31, k=(lane>>5)*8+j (32x32 analog of the
//    verified 16x16 pattern); C/D col=lane&31, row=(reg&3)+8*(reg>>2)
//    +4*(lane>>5) [m74/m101 verified]. Diag via constant-index selects.
// Predict: lse 80->71-75us, total ~153-157. absmax-fail => layout, revert.

typedef _Float16 f16x8 __attribute__((ext_vector_type(8)));   // MFMA A/B frag (4 VGPR)
typedef float    f32x16 __attribute__((ext_vector_type(16))); // MFMA C/D frag

#define NB 4
#define NN 4096
#define ND 512
#define SCALE 0.0625f
#define LOG2E 1.4426950408889634f
#define NROWS (NB * NN)            // 16384
#define NCS 4                      // column splits
#define FRAG_B 1024                // bytes per packed fragment (64 lanes x 16B)
#define TILE_B 32768               // 32-row kv group = 32 frags (K=512/16)
#define CPITCH 520                 // convert LDS row pitch (halfwords) = 1040 B
#define NIT 32                     // kv tiles per (b,cs): 1024 rows / 32

__device__ __forceinline__ void gld16(const void* g, void* l) {
    __builtin_amdgcn_global_load_lds(
        (const __attribute__((address_space(1))) unsigned int*)g,
        (__attribute__((address_space(3))) unsigned int*)l, 16, 0, 0);
}

__device__ __forceinline__ f16x8 cvt8(float4 a, float4 b) {
    f16x8 r;
    r[0] = (_Float16)a.x; r[1] = (_Float16)a.y; r[2] = (_Float16)a.z; r[3] = (_Float16)a.w;
    r[4] = (_Float16)b.x; r[5] = (_Float16)b.y; r[6] = (_Float16)b.z; r[7] = (_Float16)b.w;
    return r;
}

__device__ __forceinline__ f16x8 cvt8s(float4 a, float4 b, float s) {
    f16x8 r;
    r[0] = (_Float16)(a.x * s); r[1] = (_Float16)(a.y * s);
    r[2] = (_Float16)(a.z * s); r[3] = (_Float16)(a.w * s);
    r[4] = (_Float16)(b.x * s); r[5] = (_Float16)(b.y * s);
    r[6] = (_Float16)(b.z * s); r[7] = (_Float16)(b.w * s);
    return r;
}

// ---- kernel 1: kv fp32 -> fp16, packed in 32x32x16 B-frag order.
// One 32-row group per block (512 blocks). frag(g,kt) lane l bytes =
// kv[g*32 + (l&31)][kt*16 + (l>>5)*8 .. +8) as fp16.
__launch_bounds__(256)
__global__ void convert_kernel(const float* __restrict__ kv,
                               _Float16* __restrict__ kvp) {
    __shared__ _Float16 s[32 * CPITCH];   // 33280 hw = 66560 B
    const int g    = blockIdx.x;          // 0..511
    const int tid  = threadIdx.x;
    const int wid  = tid >> 6;
    const int lane = tid & 63;
    const int l31  = lane & 31;
    const int hi   = lane >> 5;

    #pragma unroll
    for (int i = 0; i < 8; ++i) {
        const int r = wid * 8 + i;
        const float* src = kv + ((size_t)g * 32 + r) * ND + lane * 8;
        float4 a = *(const float4*)src;
        float4 b = *(const float4*)(src + 4);
        *(f16x8*)(s + r * CPITCH + lane * 8) = cvt8(a, b);
    }
    __syncthreads();

    _Float16* dst = kvp + (size_t)g * 16384 + lane * 8;
    #pragma unroll
    for (int p = 0; p < 8; ++p) {
        const int kt = wid * 8 + p;
        f16x8 v = *(const f16x8*)(s + l31 * CPITCH + kt * 16 + hi * 8);
        *(f16x8*)(dst + kt * 512) = v;
    }
}

// ---- kernel 2: per-row sum of exp(score) over a 1024-column split + diag.
// grid (16: b*4+cs, 32: rowblock) = 512 blocks, 256 threads = 4 waves,
// 2 blocks/CU (2x32KB LDS dbuf), 2 waves/SIMD. Wave: 32 q-rows, one
// 32x32x16 MFMA per kt (32 kt of K=16), B-frags prefetched 4 kt ahead.
__launch_bounds__(256, 2)
__global__ void lse_partial_kernel(const float* __restrict__ q,
                                   const _Float16* __restrict__ kvp,
                                   float* __restrict__ partial,
                                   float* __restrict__ diagsc) {
    __shared__ char sbuf[2][TILE_B];

    const int bc = blockIdx.x;          // b*4 + cs (fastest -> spread over XCDs)
    const int b  = bc >> 2;
    const int cs = bc & 3;
    const int rb = blockIdx.y;
    const int tid  = threadIdx.x;
    const int wid  = tid >> 6;
    const int lane = tid & 63;
    const int l31  = lane & 31;
    const int hi   = lane >> 5;

    const int row0 = rb * 128 + wid * 32;    // wave's first q-row (in batch)
    // iteration whose 32-row kv tile coincides with this wave's 32 q-rows
    const int it_diag = ((row0 >> 10) == cs) ? ((row0 - cs * 1024) >> 5) : -1;

    // packed base for this (b,cs): groups [b*128 + cs*32, +32) = 32 tiles
    const char* pb  = (const char*)kvp + ((size_t)(b * 128 + cs * 32)) * TILE_B;
    const char* ssb = pb + (size_t)lane * 16;

    char* cur = sbuf[0];
    char* nxt = sbuf[1];

    // stage 32-frag tile `it_`: 8 frag-DMAs per wave. LDS dest is
    // wave-uniform base (HW adds lane*16); per-lane part lives in the
    // global source address (m104/m108).
    #define STAGE(it_, dst_)                                                  \
        do {                                                                  \
            const char* sp_ = ssb + (size_t)(it_) * TILE_B;                   \
            _Pragma("unroll")                                                 \
            for (int p_ = 0; p_ < 8; ++p_) {                                  \
                int f_ = wid * 8 + p_;                                        \
                gld16(sp_ + (size_t)f_ * FRAG_B, (dst_) + (size_t)f_ * FRAG_B); \
            }                                                                 \
        } while (0)

    // issue tile-0 DMAs first so they land under the A-frag load/convert
    STAGE(0, cur);

    // ---- A fragments: q fp32 -> fp16 scaled by s*log2e (exp2 path).
    // 32x32x16 A layout: row = lane&31, k = kt*16 + (lane>>5)*8 + j.
    f16x8 Af[32];
    {
        const float* qrow = q + ((size_t)(b * NN + row0 + l31)) * ND + hi * 8;
        #pragma unroll
        for (int kt = 0; kt < 32; ++kt) {
            float4 u0 = *(const float4*)(qrow + kt * 16);
            float4 u1 = *(const float4*)(qrow + kt * 16 + 4);
            Af[kt] = cvt8s(u0, u1, SCALE * LOG2E);
        }
    }

    float lacc[16];
    #pragma unroll
    for (int j = 0; j < 16; ++j)
        lacc[j] = 0.f;

    for (int it = 0; it < NIT; ++it) {
        f32x16 acc;
        #pragma unroll
        for (int j = 0; j < 16; ++j)
            acc[j] = 0.f;

        // tile-`it` DMA drained; all waves done READING `nxt` (it-1 compute)
        asm volatile("s_waitcnt vmcnt(0)" ::: "memory");
        __builtin_amdgcn_s_barrier();
        asm volatile("" ::: "memory");     // pin ds_reads below the barrier
        if (it + 1 < NIT) STAGE(it + 1, nxt);

        const char* lb = cur + (size_t)lane * 16;

        // ---- pipelined MFMA: one ds_read_b128 + one 32x32x16 MFMA per kt,
        // B-frags read 4 kt ahead (slot kt&3, compile-time -- rule #20).
        f16x8 pbuf[4];
        pbuf[0] = *(const f16x8*)(lb + 0 * FRAG_B);
        pbuf[1] = *(const f16x8*)(lb + 1 * FRAG_B);
        pbuf[2] = *(const f16x8*)(lb + 2 * FRAG_B);
        pbuf[3] = *(const f16x8*)(lb + 3 * FRAG_B);

        __builtin_amdgcn_s_setprio(1);
        #define KSTEP(kt_)                                                     \
            do {                                                               \
                acc = __builtin_amdgcn_mfma_f32_32x32x16_f16(                  \
                    Af[kt_], pbuf[(kt_) & 3], acc, 0, 0, 0);                   \
                if ((kt_) + 4 < 32)                                            \
                    pbuf[(kt_) & 3] =                                          \
                        *(const f16x8*)(lb + ((kt_) + 4) * FRAG_B);            \
            } while (0)
        KSTEP(0);  KSTEP(1);  KSTEP(2);  KSTEP(3);
        KSTEP(4);  KSTEP(5);  KSTEP(6);  KSTEP(7);
        KSTEP(8);  KSTEP(9);  KSTEP(10); KSTEP(11);
        KSTEP(12); KSTEP(13); KSTEP(14); KSTEP(15);
        KSTEP(16); KSTEP(17); KSTEP(18); KSTEP(19);
        KSTEP(20); KSTEP(21); KSTEP(22); KSTEP(23);
        KSTEP(24); KSTEP(25); KSTEP(26); KSTEP(27);
        KSTEP(28); KSTEP(29); KSTEP(30); KSTEP(31);
        #undef KSTEP
        __builtin_amdgcn_s_setprio(0);

        // diag: C/D col = lane&31, row = (reg&3)+8*(reg>>2)+4*hi.
        // On the aligned tile, need row == col == l31: lane eligible iff
        // ((l31>>2) ^ hi) even; then reg rr = (((l31>>2)-hi)>>1)<<2 | (l31&3).
        if (it == it_diag && ((((l31 >> 2) ^ hi) & 1) == 0)) {
            const int rr = ((((l31 >> 2) - hi) >> 1) << 2) | (l31 & 3);
            float v =
                (rr == 0)  ? acc[0]  : (rr == 1)  ? acc[1]  :
                (rr == 2)  ? acc[2]  : (rr == 3)  ? acc[3]  :
                (rr == 4)  ? acc[4]  : (rr == 5)  ? acc[5]  :
                (rr == 6)  ? acc[6]  : (rr == 7)  ? acc[7]  :
                (rr == 8)  ? acc[8]  : (rr == 9)  ? acc[9]  :
                (rr == 10) ? acc[10] : (rr == 11) ? acc[11] :
                (rr == 12) ? acc[12] : (rr == 13) ? acc[13] :
                (rr == 14) ? acc[14] : acc[15];
            diagsc[b * NN + row0 + l31] = v;   // score*log2e
        }

        // acc = score*log2e -> exp(score) = exp2(acc) = native v_exp_f32
        #pragma unroll
        for (int j = 0; j < 16; ++j)
            lacc[j] += __builtin_amdgcn_exp2f(acc[j]);

        char* t = cur; cur = nxt; nxt = t;
    }

    // reduce over the 32 kv columns held across the l31 lanes (per hi half)
    #pragma unroll
    for (int j = 0; j < 16; ++j) {
        float v = lacc[j];
        v += __shfl_xor(v, 1, 64);
        v += __shfl_xor(v, 2, 64);
        v += __shfl_xor(v, 4, 64);
        v += __shfl_xor(v, 8, 64);
        v += __shfl_xor(v, 16, 64);
        if (l31 == 0) {
            const int row = (j & 3) + 8 * (j >> 2) + 4 * hi;
            partial[(size_t)cs * NROWS + b * NN + row0 + row] = v;
        }
    }
}

// ---- kernel 3: out = exp2(diag_scaled) / sum_cs partial
__launch_bounds__(256)
__global__ void finalize_kernel(const float* __restrict__ partial,
                                const float* __restrict__ diagsc,
                                float* __restrict__ out) {
    const int idx = blockIdx.x * 256 + threadIdx.x;
    float l = 0.f;
    #pragma unroll
    for (int c = 0; c < NCS; ++c)
        l += partial[(size_t)c * NROWS + idx];
    out[idx] = exp2f(diagsc[idx]) / l;
}

extern "C" void kernel_launch(void* const* d_in, const int* in_sizes, int n_in,
                              void* d_out, int out_size, void* d_ws, size_t ws_size,
                              hipStream_t stream) {
    const float* q  = (const float*)d_in[0];
    const float* kv = (const float*)d_in[1];
    float* out = (float*)d_out;

    // ws: kvp fp16 packed [16MB] | partial f32[4][16384] | diagsc f32[16384]
    _Float16* kvp   = (_Float16*)d_ws;
    float* partial  = (float*)((char*)d_ws + (size_t)NROWS * ND * 2);
    float* diagsc   = partial + NCS * NROWS;

    convert_kernel<<<512, 256, 0, stream>>>(kv, kvp);
    lse_partial_kernel<<<dim3(16, 32), 256, 0, stream>>>(q, kvp, partial, diagsc);
    finalize_kernel<<<NROWS / 256, 256, 0, stream>>>(partial, diagsc, out);
}

// Round 11
// 162.048 us; speedup vs baseline: 1.0655x; 1.0655x over previous
//
#include <hip/hip_runtime.h>
#include <hip/hip_fp16.h>

// dot_attention: out[b,n] = exp(diag*s - lse_n), s = (D/2)^-0.5 = 1/16.
// B=4, N=4096, D=512. Inputs fp32, output fp32.
// No fp32 MFMA on CDNA4 -> fp16 convert + mfma_f32_16x16x32_f16.
//
// R18: R15 structure + FORCED A-fragment residency (asm pin).
//  - Smoking gun (seen R17, true since R7): VGPR_Count 104-112 while
//    Af[2][16] alone needs 128 VGPRs, with zero scratch traffic -> the
//    compiler REMATERIALIZES Af each iteration: re-loads q (L2, ~200cy)
//    + re-runs cvt8s per kt-step. Explains: VALUBusy 20% (512 re-convert
//    ops/wave-iter), exact neutrality of ALL LDS-side work (R8/R10/R15/
//    R16 -- the MFMA stall is the A operand from L2, not B from LDS),
//    R11's Af=256 reporting 180, and q re-reads hidden from FETCH_SIZE
//    (32MB q is L3-resident -- the L3 masking gotcha).
//  - Fix: asm volatile("" : "+v"(Af[m][k])) after the A-build. A value
//    routed through asm cannot be rematerialized from memory (rule #17);
//    cap 256 (launch_bounds(256,2)), need ~200 -> stays in registers.
//  - Everything else byte-identical to R15 (80.7us lse).
// Predict: VGPR ~200-245 (diagnostic), VALU 20->~10, MfmaUtil 36->48-60,
// lse 80->52-64us, WRITE_SIZE flat (no scratch). VGPR-jump+neutral =>
// remat latency was hidden -> K-split next. VGPR flat => pin failed.

typedef _Float16 f16x8 __attribute__((ext_vector_type(8)));  // MFMA A/B frag (4 VGPR)
typedef float    f32x4 __attribute__((ext_vector_type(4)));  // MFMA C/D frag

#define NB 4
#define NN 4096
#define ND 512
#define SCALE 0.0625f
#define LOG2E 1.4426950408889634f
#define NROWS (NB * NN)            // 16384
#define NCS 4                      // column splits
#define FRAG_B 1024                // bytes per packed fragment
#define GRP_B  16384               // bytes per 16-row group (16 frags)
#define TILE_B 32768               // 32-row tile = 2 groups
#define CPITCH 520                 // convert LDS row pitch (halfwords) = 1040 B
#define NIT 32                     // kv tiles per (b,cs): 1024 rows / 32

__device__ __forceinline__ void gld16(const void* g, void* l) {
    __builtin_amdgcn_global_load_lds(
        (const __attribute__((address_space(1))) unsigned int*)g,
        (__attribute__((address_space(3))) unsigned int*)l, 16, 0, 0);
}

__device__ __forceinline__ f16x8 cvt8(float4 a, float4 b) {
    f16x8 r;
    r[0] = (_Float16)a.x; r[1] = (_Float16)a.y; r[2] = (_Float16)a.z; r[3] = (_Float16)a.w;
    r[4] = (_Float16)b.x; r[5] = (_Float16)b.y; r[6] = (_Float16)b.z; r[7] = (_Float16)b.w;
    return r;
}

__device__ __forceinline__ f16x8 cvt8s(float4 a, float4 b, float s) {
    f16x8 r;
    r[0] = (_Float16)(a.x * s); r[1] = (_Float16)(a.y * s);
    r[2] = (_Float16)(a.z * s); r[3] = (_Float16)(a.w * s);
    r[4] = (_Float16)(b.x * s); r[5] = (_Float16)(b.y * s);
    r[6] = (_Float16)(b.z * s); r[7] = (_Float16)(b.w * s);
    return r;
}

// ---- kernel 1: kv fp32 -> fp16, packed in B-frag order via LDS transpose.
__launch_bounds__(256)
__global__ void convert_kernel(const float* __restrict__ kv,
                               _Float16* __restrict__ kvp) {
    __shared__ _Float16 s[16 * CPITCH];
    const int g    = blockIdx.x;
    const int tid  = threadIdx.x;
    const int wid  = tid >> 6;
    const int lane = tid & 63;
    const int l15  = lane & 15;
    const int quad = lane >> 4;

    #pragma unroll
    for (int i = 0; i < 4; ++i) {
        const int r = wid * 4 + i;
        const float* src = kv + ((size_t)g * 16 + r) * ND + lane * 8;
        float4 a = *(const float4*)src;
        float4 b = *(const float4*)(src + 4);
        *(f16x8*)(s + r * CPITCH + lane * 8) = cvt8(a, b);
    }
    __syncthreads();

    _Float16* dst = kvp + (size_t)g * 8192 + lane * 8;
    #pragma unroll
    for (int p = 0; p < 4; ++p) {
        const int kt = wid * 4 + p;
        f16x8 v = *(const f16x8*)(s + l15 * CPITCH + kt * 32 + quad * 8);
        *(f16x8*)(dst + kt * 512) = v;
    }
}

// ---- kernel 2: per-row sum of exp(score) over a 1024-column split + diag.
// grid (16: b*4+cs, 32: rowblock) = 512 blocks, 256 threads = 4 waves,
// 2 blocks/CU (2x32KB LDS dbuf), 2 waves/SIMD. Wave: 32 q-rows, Af PINNED
// in 128 VGPRs. Per iter: one 32-row kv tile, B-frags prefetched 4 kt ahead.
__launch_bounds__(256, 2)
__global__ void lse_partial_kernel(const float* __restrict__ q,
                                   const _Float16* __restrict__ kvp,
                                   float* __restrict__ partial,
                                   float* __restrict__ diagsc) {
    __shared__ char sbuf[2][TILE_B];

    const int bc = blockIdx.x;          // b*4 + cs (fastest -> spread over XCDs)
    const int b  = bc >> 2;
    const int cs = bc & 3;
    const int rb = blockIdx.y;
    const int tid  = threadIdx.x;
    const int wid  = tid >> 6;
    const int lane = tid & 63;
    const int l15  = lane & 15;
    const int quad = lane >> 4;

    const int row0 = rb * 128 + wid * 32;    // wave's first q-row (in batch)
    // iteration whose 32-col kv tile coincides with this wave's 32 q-rows
    const int it_diag = ((row0 >> 10) == cs) ? ((row0 - cs * 1024) >> 5) : -1;

    // packed base for this (b,cs): groups [b*256 + cs*64, +64) = 32 tiles
    const char* pb  = (const char*)kvp + ((size_t)(b * 256 + cs * 64)) * GRP_B;
    const char* ssb = pb + (size_t)lane * 16;

    char* cur = sbuf[0];
    char* nxt = sbuf[1];

    // stage 32-frag tile `it_`: 8 frag-DMAs per wave. LDS dest is
    // wave-uniform base (HW adds lane*16); per-lane part lives in the
    // global source address (m104/m108).
    #define STAGE(it_, dst_)                                                  \
        do {                                                                  \
            const char* sp_ = ssb + (size_t)(it_) * TILE_B;                   \
            _Pragma("unroll")                                                 \
            for (int p_ = 0; p_ < 8; ++p_) {                                  \
                int f_ = wid * 8 + p_;                                        \
                gld16(sp_ + (size_t)f_ * FRAG_B, (dst_) + (size_t)f_ * FRAG_B); \
            }                                                                 \
        } while (0)

    // issue tile-0 DMAs first so they land under the A-frag load/convert
    STAGE(0, cur);

    // ---- A fragments: q fp32 -> fp16 scaled by s*log2e (exp2 path).
    f16x8 Af[2][16];
    #pragma unroll
    for (int m = 0; m < 2; ++m) {
        const float* qrow = q + ((size_t)(b * NN + row0 + m * 16 + l15)) * ND + quad * 8;
        #pragma unroll
        for (int k = 0; k < 16; ++k) {
            float4 u0 = *(const float4*)(qrow + k * 32);
            float4 u1 = *(const float4*)(qrow + k * 32 + 4);
            Af[m][k] = cvt8s(u0, u1, SCALE * LOG2E);
        }
    }

    // ---- PIN Af in registers: a value that has passed through asm cannot
    // be rematerialized from memory (the load+cvt chain is severed), so the
    // compiler must keep all 128 VGPRs live across the main loop.
    #pragma unroll
    for (int m = 0; m < 2; ++m)
        #pragma unroll
        for (int k = 0; k < 16; ++k)
            asm volatile("" : "+v"(Af[m][k]));

    float lacc[2][4];
    #pragma unroll
    for (int m = 0; m < 2; ++m)
        #pragma unroll
        for (int j = 0; j < 4; ++j)
            lacc[m][j] = 0.f;

    for (int it = 0; it < NIT; ++it) {
        f32x4 acc[2][2];
        #pragma unroll
        for (int m = 0; m < 2; ++m)
            #pragma unroll
            for (int nf = 0; nf < 2; ++nf)
                acc[m][nf] = (f32x4){0.f, 0.f, 0.f, 0.f};

        // tile-`it` DMA drained; all waves done READING `nxt` (it-1 compute)
        asm volatile("s_waitcnt vmcnt(0)" ::: "memory");
        __builtin_amdgcn_s_barrier();
        asm volatile("" ::: "memory");     // pin ds_reads below the barrier
        if (it + 1 < NIT) STAGE(it + 1, nxt);

        const char* lb = cur + (size_t)lane * 16;

        // ---- software-pipelined MFMA: B-frags read 4 kt-steps ahead
        // (8 ds_read_b128 in flight). Slot index kt&3, compile-time
        // (rule #20). In-order DS returns -> counted lgkmcnt per step.
        f16x8 pb0[4], pb1[4];
        pb0[0] = *(const f16x8*)(lb + 0 * FRAG_B);
        pb1[0] = *(const f16x8*)(lb + GRP_B + 0 * FRAG_B);
        pb0[1] = *(const f16x8*)(lb + 1 * FRAG_B);
        pb1[1] = *(const f16x8*)(lb + GRP_B + 1 * FRAG_B);
        pb0[2] = *(const f16x8*)(lb + 2 * FRAG_B);
        pb1[2] = *(const f16x8*)(lb + GRP_B + 2 * FRAG_B);
        pb0[3] = *(const f16x8*)(lb + 3 * FRAG_B);
        pb1[3] = *(const f16x8*)(lb + GRP_B + 3 * FRAG_B);

        __builtin_amdgcn_s_setprio(1);
        #define KSTEP(kt_)                                                     \
            do {                                                               \
                acc[0][0] = __builtin_amdgcn_mfma_f32_16x16x32_f16(            \
                    Af[0][kt_], pb0[(kt_) & 3], acc[0][0], 0, 0, 0);           \
                acc[1][0] = __builtin_amdgcn_mfma_f32_16x16x32_f16(            \
                    Af[1][kt_], pb0[(kt_) & 3], acc[1][0], 0, 0, 0);           \
                acc[0][1] = __builtin_amdgcn_mfma_f32_16x16x32_f16(            \
                    Af[0][kt_], pb1[(kt_) & 3], acc[0][1], 0, 0, 0);           \
                acc[1][1] = __builtin_amdgcn_mfma_f32_16x16x32_f16(            \
                    Af[1][kt_], pb1[(kt_) & 3], acc[1][1], 0, 0, 0);           \
                if ((kt_) + 4 < 16) {                                          \
                    pb0[(kt_) & 3] =                                           \
                        *(const f16x8*)(lb + ((kt_) + 4) * FRAG_B);            \
                    pb1[(kt_) & 3] =                                           \
                        *(const f16x8*)(lb + GRP_B + ((kt_) + 4) * FRAG_B);    \
                }                                                              \
            } while (0)
        KSTEP(0);  KSTEP(1);  KSTEP(2);  KSTEP(3);
        KSTEP(4);  KSTEP(5);  KSTEP(6);  KSTEP(7);
        KSTEP(8);  KSTEP(9);  KSTEP(10); KSTEP(11);
        KSTEP(12); KSTEP(13); KSTEP(14); KSTEP(15);
        #undef KSTEP
        __builtin_amdgcn_s_setprio(0);

        // diag extraction: C/D row = quad*4+j, col = nf*16+l15. On the
        // aligned iter, row==col  =>  nf==m, l15==quad*4+j.
        if (it == it_diag) {
            if ((l15 >> 2) == quad) {
                const int j = l15 & 3;
                float d0 = (j == 0) ? acc[0][0][0] : (j == 1) ? acc[0][0][1]
                         : (j == 2) ? acc[0][0][2] : acc[0][0][3];
                float d1 = (j == 0) ? acc[1][1][0] : (j == 1) ? acc[1][1][1]
                         : (j == 2) ? acc[1][1][2] : acc[1][1][3];
                diagsc[b * NN + row0 + l15]      = d0;   // score*log2e
                diagsc[b * NN + row0 + 16 + l15] = d1;
            }
        }

        // acc = score*log2e -> exp(score) = exp2(acc) = native v_exp_f32
        #pragma unroll
        for (int m = 0; m < 2; ++m)
            #pragma unroll
            for (int nf = 0; nf < 2; ++nf)
                #pragma unroll
                for (int j = 0; j < 4; ++j)
                    lacc[m][j] += __builtin_amdgcn_exp2f(acc[m][nf][j]);

        char* t = cur; cur = nxt; nxt = t;
    }

    // reduce over the 16 columns held across l15 lanes
    #pragma unroll
    for (int m = 0; m < 2; ++m)
        #pragma unroll
        for (int j = 0; j < 4; ++j) {
            float v = lacc[m][j];
            v += __shfl_xor(v, 1, 64);
            v += __shfl_xor(v, 2, 64);
            v += __shfl_xor(v, 4, 64);
            v += __shfl_xor(v, 8, 64);
            if (l15 == 0)
                partial[(size_t)cs * NROWS + b * NN + row0 + m * 16 + quad * 4 + j] = v;
        }
}

// ---- kernel 3: out = exp2(diag_scaled) / sum_cs partial
__launch_bounds__(256)
__global__ void finalize_kernel(const float* __restrict__ partial,
                                const float* __restrict__ diagsc,
                                float* __restrict__ out) {
    const int idx = blockIdx.x * 256 + threadIdx.x;
    float l = 0.f;
    #pragma unroll
    for (int c = 0; c < NCS; ++c)
        l += partial[(size_t)c * NROWS + idx];
    out[idx] = exp2f(diagsc[idx]) / l;
}

extern "C" void kernel_launch(void* const* d_in, const int* in_sizes, int n_in,
                              void* d_out, int out_size, void* d_ws, size_t ws_size,
                              hipStream_t stream) {
    const float* q  = (const float*)d_in[0];
    const float* kv = (const float*)d_in[1];
    float* out = (float*)d_out;

    // ws: kvp fp16 packed [16MB] | partial f32[4][16384] | diagsc f32[16384]
    _Float16* kvp   = (_Float16*)d_ws;
    float* partial  = (float*)((char*)d_ws + (size_t)NROWS * ND * 2);
    float* diagsc   = partial + NCS * NROWS;

    convert_kernel<<<1024, 256, 0, stream>>>(kv, kvp);
    lse_partial_kernel<<<dim3(16, 32), 256, 0, stream>>>(q, kvp, partial, diagsc);
    finalize_kernel<<<NROWS / 256, 256, 0, stream>>>(partial, diagsc, out);
}